// Round 1
// baseline (2299.273 us; speedup 1.0000x reference)
//
#include <hip/hip_runtime.h>

namespace {

constexpr int Un = 100000;
constexpr int In = 50000;
constexpr int Nn = 150000;
constexpr int D  = 64;
constexpr int Ln = 3;
constexpr int En = 2000000;
constexpr int CHUNK = 1024;
constexpr int NB = (Nn + CHUNK - 1) / CHUNK;  // 147 scan blocks

__global__ void count_kernel(const int* __restrict__ rows, int* __restrict__ deg) {
    int e = blockIdx.x * blockDim.x + threadIdx.x;
    if (e < En) atomicAdd(&deg[rows[e]], 1);
}

__global__ void scan_partial(const int* __restrict__ deg, float* __restrict__ d_is,
                             int* __restrict__ bsum) {
    int tid = threadIdx.x;
    int base = blockIdx.x * CHUNK + tid * 4;
    int s = 0;
#pragma unroll
    for (int i = 0; i < 4; ++i) {
        int idx = base + i;
        if (idx < Nn) {
            int d = deg[idx];
            s += d;
            d_is[idx] = d > 0 ? rsqrtf((float)d) : 0.f;
        }
    }
    __shared__ int sh[256];
    sh[tid] = s;
    __syncthreads();
    for (int o = 128; o > 0; o >>= 1) {
        if (tid < o) sh[tid] += sh[tid + o];
        __syncthreads();
    }
    if (tid == 0) bsum[blockIdx.x] = sh[0];
}

__global__ void scan_top(int* __restrict__ bsum, int* __restrict__ row_ptr) {
    __shared__ int sh[256];
    int tid = threadIdx.x;
    int v = (tid < NB) ? bsum[tid] : 0;
    sh[tid] = v;
    __syncthreads();
    for (int o = 1; o < 256; o <<= 1) {
        int t = (tid >= o) ? sh[tid - o] : 0;
        __syncthreads();
        sh[tid] += t;
        __syncthreads();
    }
    if (tid < NB) bsum[tid] = sh[tid] - v;  // exclusive
    if (tid == 255) row_ptr[Nn] = sh[255];  // == En
}

__global__ void scan_final(const int* __restrict__ deg, const int* __restrict__ bsum,
                           int* __restrict__ row_ptr) {
    int tid = threadIdx.x;
    int base = blockIdx.x * CHUNK + tid * 4;
    int v[4];
    int ts = 0;
#pragma unroll
    for (int i = 0; i < 4; ++i) {
        int idx = base + i;
        v[i] = (idx < Nn) ? deg[idx] : 0;
        ts += v[i];
    }
    __shared__ int sh[256];
    sh[tid] = ts;
    __syncthreads();
    for (int o = 1; o < 256; o <<= 1) {
        int t = (tid >= o) ? sh[tid - o] : 0;
        __syncthreads();
        sh[tid] += t;
        __syncthreads();
    }
    int excl = bsum[blockIdx.x] + sh[tid] - ts;
#pragma unroll
    for (int i = 0; i < 4; ++i) {
        int idx = base + i;
        if (idx < Nn) row_ptr[idx] = excl;
        excl += v[i];
    }
}

__global__ void fill_kernel(const int* __restrict__ rows, const int* __restrict__ cols,
                            const int* __restrict__ row_ptr, int* __restrict__ fillc,
                            const float* __restrict__ d_is,
                            int* __restrict__ col_s, float* __restrict__ val_s) {
    int e = blockIdx.x * blockDim.x + threadIdx.x;
    if (e >= En) return;
    int r = rows[e], c = cols[e];
    int p = row_ptr[r] + atomicAdd(&fillc[r], 1);
    col_s[p] = c;
    val_s[p] = d_is[r] * d_is[c];
}

// wave (64 lanes) per row, lane = dim.  B[r] = sum_e val * A[col]; also 1/max(||B[r]||,eps)
__global__ __launch_bounds__(256) void spmm_gnn(const float* __restrict__ A, float* __restrict__ B,
                                                const int* __restrict__ row_ptr,
                                                const int* __restrict__ col_s,
                                                const float* __restrict__ val_s,
                                                float* __restrict__ inv_norm) {
    int r = (blockIdx.x * 256 + threadIdx.x) >> 6;
    int lane = threadIdx.x & 63;
    if (r >= Nn) return;
    int s = row_ptr[r], t = row_ptr[r + 1];
    float acc = 0.f;
    for (int j = s; j < t; ++j) {
        int c = col_s[j];
        acc += val_s[j] * A[(size_t)c * D + lane];
    }
    B[(size_t)r * D + lane] = acc;
    float sq = acc * acc;
    for (int o = 32; o > 0; o >>= 1) sq += __shfl_xor(sq, o);
    if (lane == 0) inv_norm[r] = 1.f / fmaxf(sqrtf(sq), 1e-12f);
}

// per-edge cosine score + per-row rowsum -> d_inv
__global__ __launch_bounds__(256) void score_kernel(const float* __restrict__ B,
                                                    const float* __restrict__ inv_norm,
                                                    const int* __restrict__ row_ptr,
                                                    const int* __restrict__ col_s,
                                                    float* __restrict__ scores,
                                                    float* __restrict__ d_inv) {
    int r = (blockIdx.x * 256 + threadIdx.x) >> 6;
    int lane = threadIdx.x & 63;
    if (r >= Nn) return;
    int s = row_ptr[r], t = row_ptr[r + 1];
    float br = B[(size_t)r * D + lane];
    float ir = inv_norm[r];
    float rowsum = 0.f;
    for (int j = s; j < t; ++j) {
        int c = col_s[j];
        float d = br * B[(size_t)c * D + lane];
        for (int o = 32; o > 0; o >>= 1) d += __shfl_xor(d, o);
        float sc = (d * ir * inv_norm[c] + 1.f) * 0.5f;
        if (lane == 0) scores[j] = sc;
        rowsum += sc;
    }
    if (lane == 0) d_inv[r] = rowsum > 0.f ? 1.f / rowsum : 0.f;
}

// fine = d_inv[r] * sum_e score * A[col]; cur_new = gnn + fine (in-place in B);
// acc += cur_new (in d_out); write fine to its output slot
__global__ __launch_bounds__(256) void fine_kernel(const float* __restrict__ A, float* __restrict__ B,
                                                   const int* __restrict__ row_ptr,
                                                   const int* __restrict__ col_s,
                                                   const float* __restrict__ scores,
                                                   const float* __restrict__ d_inv,
                                                   float* __restrict__ out, int layer) {
    int r = (blockIdx.x * 256 + threadIdx.x) >> 6;
    int lane = threadIdx.x & 63;
    if (r >= Nn) return;
    int s = row_ptr[r], t = row_ptr[r + 1];
    float f = 0.f;
    for (int j = s; j < t; ++j) {
        int c = col_s[j];
        f += scores[j] * A[(size_t)c * D + lane];
    }
    f *= d_inv[r];
    size_t ro = (size_t)r * D + lane;
    float curnew = B[ro] + f;
    B[ro] = curnew;
    out[ro] += curnew;
    size_t fo;
    if (r < Un)
        fo = (size_t)Nn * D + (size_t)layer * Un * D + (size_t)r * D + lane;
    else
        fo = (size_t)Nn * D + (size_t)Ln * Un * D + (size_t)layer * In * D + (size_t)(r - Un) * D + lane;
    out[fo] = f;
}

}  // namespace

extern "C" void kernel_launch(void* const* d_in, const int* in_sizes, int n_in,
                              void* d_out, int out_size, void* d_ws, size_t ws_size,
                              hipStream_t stream) {
    const float* user_emb = (const float*)d_in[0];
    const float* item_emb = (const float*)d_in[1];
    const int* rows = (const int*)d_in[2];
    const int* cols = (const int*)d_in[3];
    float* out = (float*)d_out;

    char* ws = (char*)d_ws;
    size_t off = 0;
    auto alloc = [&](size_t bytes) -> void* {
        void* p = ws + off;
        off += (bytes + 255) & ~size_t(255);
        return p;
    };
    float* curA    = (float*)alloc((size_t)Nn * D * 4);   // 38.4 MB
    float* curB    = (float*)alloc((size_t)Nn * D * 4);   // 38.4 MB
    int*   col_s   = (int*)  alloc((size_t)En * 4);       // 8 MB
    float* val_s   = (float*)alloc((size_t)En * 4);       // 8 MB
    float* scores  = (float*)alloc((size_t)En * 4);       // 8 MB
    int*   deg     = (int*)  alloc((size_t)Nn * 4);
    int*   row_ptr = (int*)  alloc((size_t)(Nn + 1) * 4);
    int*   fillc   = (int*)  alloc((size_t)Nn * 4);
    float* d_is    = (float*)alloc((size_t)Nn * 4);
    float* inv_norm= (float*)alloc((size_t)Nn * 4);
    float* d_inv   = (float*)alloc((size_t)Nn * 4);
    int*   bsum    = (int*)  alloc(4096);
    (void)ws_size; (void)in_sizes; (void)n_in; (void)out_size; (void)d_inv;

    // cur = emb0; acc (d_out) = emb0
    hipMemcpyAsync(curA, user_emb, (size_t)Un * D * 4, hipMemcpyDeviceToDevice, stream);
    hipMemcpyAsync(curA + (size_t)Un * D, item_emb, (size_t)In * D * 4, hipMemcpyDeviceToDevice, stream);
    hipMemcpyAsync(out, user_emb, (size_t)Un * D * 4, hipMemcpyDeviceToDevice, stream);
    hipMemcpyAsync(out + (size_t)Un * D, item_emb, (size_t)In * D * 4, hipMemcpyDeviceToDevice, stream);
    hipMemsetAsync(deg, 0, (size_t)Nn * 4, stream);
    hipMemsetAsync(fillc, 0, (size_t)Nn * 4, stream);

    const int EB = (En + 255) / 256;
    count_kernel<<<EB, 256, 0, stream>>>(rows, deg);
    scan_partial<<<NB, 256, 0, stream>>>(deg, d_is, bsum);
    scan_top<<<1, 256, 0, stream>>>(bsum, row_ptr);
    scan_final<<<NB, 256, 0, stream>>>(deg, bsum, row_ptr);
    fill_kernel<<<EB, 256, 0, stream>>>(rows, cols, row_ptr, fillc, d_is, col_s, val_s);

    const int RB = Nn / 4;  // 37500 blocks, 4 waves/block, 1 wave/row
    float* A = curA;
    float* B = curB;
    for (int l = 0; l < Ln; ++l) {
        spmm_gnn<<<RB, 256, 0, stream>>>(A, B, row_ptr, col_s, val_s, inv_norm);
        score_kernel<<<RB, 256, 0, stream>>>(B, inv_norm, row_ptr, col_s, scores, d_inv);
        fine_kernel<<<RB, 256, 0, stream>>>(A, B, row_ptr, col_s, scores, d_inv, out, l);
        float* tmp = A; A = B; B = tmp;
    }
}

// Round 2
// 1227.659 us; speedup vs baseline: 1.8729x; 1.8729x over previous
//
#include <hip/hip_runtime.h>

namespace {

typedef unsigned short u16;

constexpr int Un = 100000;
constexpr int In = 50000;
constexpr int Nn = 150000;
constexpr int D  = 64;
constexpr int Ln = 3;
constexpr int En = 2000000;
constexpr int CHUNK = 1024;
constexpr int NB = (Nn + CHUNK - 1) / CHUNK;  // 147 scan blocks

__device__ __forceinline__ float bf2f(u16 u) {
    return __uint_as_float(((unsigned)u) << 16);
}
__device__ __forceinline__ u16 f2bf(float f) {
    unsigned u = __float_as_uint(f);
    unsigned r = (u + 0x7FFFu + ((u >> 16) & 1u)) >> 16;
    return (u16)r;
}

__global__ void count_kernel(const int* __restrict__ rows, int* __restrict__ deg) {
    int e = blockIdx.x * blockDim.x + threadIdx.x;
    if (e < En) atomicAdd(&deg[rows[e]], 1);
}

__global__ void scan_partial(const int* __restrict__ deg, float* __restrict__ d_is,
                             int* __restrict__ bsum) {
    int tid = threadIdx.x;
    int base = blockIdx.x * CHUNK + tid * 4;
    int s = 0;
#pragma unroll
    for (int i = 0; i < 4; ++i) {
        int idx = base + i;
        if (idx < Nn) {
            int d = deg[idx];
            s += d;
            d_is[idx] = d > 0 ? rsqrtf((float)d) : 0.f;
        }
    }
    __shared__ int sh[256];
    sh[tid] = s;
    __syncthreads();
    for (int o = 128; o > 0; o >>= 1) {
        if (tid < o) sh[tid] += sh[tid + o];
        __syncthreads();
    }
    if (tid == 0) bsum[blockIdx.x] = sh[0];
}

__global__ void scan_top(int* __restrict__ bsum, int* __restrict__ row_ptr) {
    __shared__ int sh[256];
    int tid = threadIdx.x;
    int v = (tid < NB) ? bsum[tid] : 0;
    sh[tid] = v;
    __syncthreads();
    for (int o = 1; o < 256; o <<= 1) {
        int t = (tid >= o) ? sh[tid - o] : 0;
        __syncthreads();
        sh[tid] += t;
        __syncthreads();
    }
    if (tid < NB) bsum[tid] = sh[tid] - v;  // exclusive
    if (tid == 255) row_ptr[Nn] = sh[255];  // == En
}

__global__ void scan_final(const int* __restrict__ deg, const int* __restrict__ bsum,
                           int* __restrict__ row_ptr) {
    int tid = threadIdx.x;
    int base = blockIdx.x * CHUNK + tid * 4;
    int v[4];
    int ts = 0;
#pragma unroll
    for (int i = 0; i < 4; ++i) {
        int idx = base + i;
        v[i] = (idx < Nn) ? deg[idx] : 0;
        ts += v[i];
    }
    __shared__ int sh[256];
    sh[tid] = ts;
    __syncthreads();
    for (int o = 1; o < 256; o <<= 1) {
        int t = (tid >= o) ? sh[tid - o] : 0;
        __syncthreads();
        sh[tid] += t;
        __syncthreads();
    }
    int excl = bsum[blockIdx.x] + sh[tid] - ts;
#pragma unroll
    for (int i = 0; i < 4; ++i) {
        int idx = base + i;
        if (idx < Nn) row_ptr[idx] = excl;
        excl += v[i];
    }
}

__global__ void fill_kernel(const int* __restrict__ rows, const int* __restrict__ cols,
                            const int* __restrict__ row_ptr, int* __restrict__ fillc,
                            const float* __restrict__ d_is,
                            int* __restrict__ col_s, float* __restrict__ val_s) {
    int e = blockIdx.x * blockDim.x + threadIdx.x;
    if (e >= En) return;
    int r = rows[e], c = cols[e];
    int p = row_ptr[r] + atomicAdd(&fillc[r], 1);
    col_s[p] = c;
    val_s[p] = d_is[r] * d_is[c];
}

// emb0 -> out (acc, f32) and cur (bf16)
__global__ void init_kernel(const float* __restrict__ ue, const float* __restrict__ ie,
                            float* __restrict__ out, u16* __restrict__ cur) {
    int i = (blockIdx.x * 256 + threadIdx.x) * 4;
    if (i >= Nn * D) return;
    const float* src = (i < Un * D) ? (ue + i) : (ie + (i - Un * D));
    float4 v = *(const float4*)src;
    *(float4*)(out + i) = v;
    ushort4 q;
    q.x = f2bf(v.x); q.y = f2bf(v.y); q.z = f2bf(v.z); q.w = f2bf(v.w);
    *(ushort4*)(cur + i) = q;
}

// wave per row; 4 edge-groups of 16 lanes; lane holds dims 4l..4l+3.
// B[r] = sum val*A[col] (bf16 in, f32 acc, bf16 out); inv_norm from f32 acc.
__global__ __launch_bounds__(256) void spmm_gnn(const u16* __restrict__ A, u16* __restrict__ B,
                                                const int* __restrict__ row_ptr,
                                                const int* __restrict__ col_s,
                                                const float* __restrict__ val_s,
                                                float* __restrict__ inv_norm) {
    int r = (blockIdx.x * 256 + threadIdx.x) >> 6;
    if (r >= Nn) return;
    int lane = threadIdx.x & 63;
    int g = lane >> 4, l = lane & 15;
    int s = row_ptr[r], t = row_ptr[r + 1];
    float a0 = 0.f, a1 = 0.f, a2 = 0.f, a3 = 0.f;
    for (int j = s + g; j < t; j += 4) {
        int c = col_s[j];
        float v = val_s[j];
        ushort4 q = *(const ushort4*)(A + (size_t)c * D + l * 4);
        a0 += v * bf2f(q.x); a1 += v * bf2f(q.y);
        a2 += v * bf2f(q.z); a3 += v * bf2f(q.w);
    }
    // reduce across the 4 edge-groups
    a0 += __shfl_xor(a0, 16); a1 += __shfl_xor(a1, 16);
    a2 += __shfl_xor(a2, 16); a3 += __shfl_xor(a3, 16);
    a0 += __shfl_xor(a0, 32); a1 += __shfl_xor(a1, 32);
    a2 += __shfl_xor(a2, 32); a3 += __shfl_xor(a3, 32);
    float sq = a0 * a0 + a1 * a1 + a2 * a2 + a3 * a3;
    sq += __shfl_xor(sq, 1); sq += __shfl_xor(sq, 2);
    sq += __shfl_xor(sq, 4); sq += __shfl_xor(sq, 8);
    if (g == 0) {
        ushort4 q;
        q.x = f2bf(a0); q.y = f2bf(a1); q.z = f2bf(a2); q.w = f2bf(a3);
        *(ushort4*)(B + (size_t)r * D + l * 4) = q;
        if (l == 0) inv_norm[r] = 1.f / fmaxf(sqrtf(sq), 1e-12f);
    }
}

// wave per row; 4 edges in parallel (16 lanes each); 1 ds-op/edge reduce.
__global__ __launch_bounds__(256) void score_kernel(const u16* __restrict__ B,
                                                    const float* __restrict__ inv_norm,
                                                    const int* __restrict__ row_ptr,
                                                    const int* __restrict__ col_s,
                                                    float* __restrict__ scores,
                                                    float* __restrict__ d_inv) {
    int r = (blockIdx.x * 256 + threadIdx.x) >> 6;
    if (r >= Nn) return;
    int lane = threadIdx.x & 63;
    int g = lane >> 4, l = lane & 15;
    int s = row_ptr[r], t = row_ptr[r + 1];
    ushort4 qb = *(const ushort4*)(B + (size_t)r * D + l * 4);
    float b0 = bf2f(qb.x), b1 = bf2f(qb.y), b2 = bf2f(qb.z), b3 = bf2f(qb.w);
    float ir = inv_norm[r];
    float rowsum = 0.f;
    int nit = (t - s + 3) >> 2;
    for (int i = 0; i < nit; ++i) {
        int j = s + i * 4 + g;
        bool valid = j < t;
        int jc = valid ? j : (t - 1);
        int c = col_s[jc];
        ushort4 qc = *(const ushort4*)(B + (size_t)c * D + l * 4);
        float d = b0 * bf2f(qc.x) + b1 * bf2f(qc.y) + b2 * bf2f(qc.z) + b3 * bf2f(qc.w);
        d += __shfl_xor(d, 1); d += __shfl_xor(d, 2);
        d += __shfl_xor(d, 4); d += __shfl_xor(d, 8);
        float sc = (d * ir * inv_norm[c] + 1.f) * 0.5f;
        if (valid) {
            rowsum += sc;
            if (l == 0) scores[j] = sc;
        }
    }
    rowsum += __shfl_xor(rowsum, 16);
    rowsum += __shfl_xor(rowsum, 32);
    if (lane == 0) d_inv[r] = rowsum > 0.f ? 1.f / rowsum : 0.f;
}

// fine = d_inv[r] * sum sc*A[col]; cur_new = gnn + fine (in-place bf16 in B);
// acc (f32, d_out) += cur_new; fine (f32) to its output slot.
__global__ __launch_bounds__(256) void fine_kernel(const u16* __restrict__ A, u16* __restrict__ B,
                                                   const int* __restrict__ row_ptr,
                                                   const int* __restrict__ col_s,
                                                   const float* __restrict__ scores,
                                                   const float* __restrict__ d_inv,
                                                   float* __restrict__ out, int layer) {
    int r = (blockIdx.x * 256 + threadIdx.x) >> 6;
    if (r >= Nn) return;
    int lane = threadIdx.x & 63;
    int g = lane >> 4, l = lane & 15;
    int s = row_ptr[r], t = row_ptr[r + 1];
    float f0 = 0.f, f1 = 0.f, f2 = 0.f, f3 = 0.f;
    for (int j = s + g; j < t; j += 4) {
        int c = col_s[j];
        float sc = scores[j];
        ushort4 q = *(const ushort4*)(A + (size_t)c * D + l * 4);
        f0 += sc * bf2f(q.x); f1 += sc * bf2f(q.y);
        f2 += sc * bf2f(q.z); f3 += sc * bf2f(q.w);
    }
    f0 += __shfl_xor(f0, 16); f1 += __shfl_xor(f1, 16);
    f2 += __shfl_xor(f2, 16); f3 += __shfl_xor(f3, 16);
    f0 += __shfl_xor(f0, 32); f1 += __shfl_xor(f1, 32);
    f2 += __shfl_xor(f2, 32); f3 += __shfl_xor(f3, 32);
    float di = d_inv[r];
    f0 *= di; f1 *= di; f2 *= di; f3 *= di;
    if (g == 0) {
        size_t ro = (size_t)r * D + l * 4;
        ushort4 qb = *(const ushort4*)(B + ro);
        float c0 = bf2f(qb.x) + f0, c1 = bf2f(qb.y) + f1;
        float c2 = bf2f(qb.z) + f2, c3 = bf2f(qb.w) + f3;
        ushort4 qn;
        qn.x = f2bf(c0); qn.y = f2bf(c1); qn.z = f2bf(c2); qn.w = f2bf(c3);
        *(ushort4*)(B + ro) = qn;
        float4* av = (float4*)(out + ro);
        float4 a = *av;
        a.x += c0; a.y += c1; a.z += c2; a.w += c3;
        *av = a;
        size_t fo;
        if (r < Un)
            fo = (size_t)Nn * D + (size_t)layer * Un * D + (size_t)r * D + l * 4;
        else
            fo = (size_t)Nn * D + (size_t)Ln * Un * D + (size_t)layer * In * D
                 + (size_t)(r - Un) * D + l * 4;
        float4 fv; fv.x = f0; fv.y = f1; fv.z = f2; fv.w = f3;
        *(float4*)(out + fo) = fv;
    }
}

}  // namespace

extern "C" void kernel_launch(void* const* d_in, const int* in_sizes, int n_in,
                              void* d_out, int out_size, void* d_ws, size_t ws_size,
                              hipStream_t stream) {
    const float* user_emb = (const float*)d_in[0];
    const float* item_emb = (const float*)d_in[1];
    const int* rows = (const int*)d_in[2];
    const int* cols = (const int*)d_in[3];
    float* out = (float*)d_out;

    char* ws = (char*)d_ws;
    size_t off = 0;
    auto alloc = [&](size_t bytes) -> void* {
        void* p = ws + off;
        off += (bytes + 255) & ~size_t(255);
        return p;
    };
    u16*   curA    = (u16*)  alloc((size_t)Nn * D * 2);   // 19.2 MB
    u16*   curB    = (u16*)  alloc((size_t)Nn * D * 2);   // 19.2 MB
    int*   col_s   = (int*)  alloc((size_t)En * 4);       // 8 MB
    float* val_s   = (float*)alloc((size_t)En * 4);       // 8 MB
    float* scores  = (float*)alloc((size_t)En * 4);       // 8 MB
    int*   deg     = (int*)  alloc((size_t)Nn * 4);
    int*   row_ptr = (int*)  alloc((size_t)(Nn + 1) * 4);
    int*   fillc   = (int*)  alloc((size_t)Nn * 4);
    float* d_is    = (float*)alloc((size_t)Nn * 4);
    float* inv_norm= (float*)alloc((size_t)Nn * 4);
    float* d_inv   = (float*)alloc((size_t)Nn * 4);
    int*   bsum    = (int*)  alloc(4096);
    (void)ws_size; (void)in_sizes; (void)n_in; (void)out_size;

    hipMemsetAsync(deg, 0, (size_t)Nn * 4, stream);
    hipMemsetAsync(fillc, 0, (size_t)Nn * 4, stream);

    init_kernel<<<(Nn * D / 4 + 255) / 256, 256, 0, stream>>>(user_emb, item_emb, out, curA);

    const int EB = (En + 255) / 256;
    count_kernel<<<EB, 256, 0, stream>>>(rows, deg);
    scan_partial<<<NB, 256, 0, stream>>>(deg, d_is, bsum);
    scan_top<<<1, 256, 0, stream>>>(bsum, row_ptr);
    scan_final<<<NB, 256, 0, stream>>>(deg, bsum, row_ptr);
    fill_kernel<<<EB, 256, 0, stream>>>(rows, cols, row_ptr, fillc, d_is, col_s, val_s);

    const int RB = Nn / 4;  // 37500 blocks, 4 waves/block, 1 wave/row
    u16* A = curA;
    u16* B = curB;
    for (int l = 0; l < Ln; ++l) {
        spmm_gnn<<<RB, 256, 0, stream>>>(A, B, row_ptr, col_s, val_s, inv_norm);
        score_kernel<<<RB, 256, 0, stream>>>(B, inv_norm, row_ptr, col_s, scores, d_inv);
        fine_kernel<<<RB, 256, 0, stream>>>(A, B, row_ptr, col_s, scores, d_inv, out, l);
        u16* tmp = A; A = B; B = tmp;
    }
}

// Round 4
// 972.951 us; speedup vs baseline: 2.3632x; 1.2618x over previous
//
#include <hip/hip_runtime.h>

namespace {

typedef unsigned short u16;

constexpr int Un = 100000;
constexpr int In = 50000;
constexpr int Nn = 150000;
constexpr int D  = 64;
constexpr int Ln = 3;
constexpr int En = 2000000;
constexpr int CHUNK = 1024;
constexpr int NB = (Nn + CHUNK - 1) / CHUNK;  // 147 scan blocks

__device__ __forceinline__ float bf2f(u16 u) {
    return __uint_as_float(((unsigned)u) << 16);
}
__device__ __forceinline__ u16 f2bf(float f) {
    unsigned u = __float_as_uint(f);
    unsigned r = (u + 0x7FFFu + ((u >> 16) & 1u)) >> 16;
    return (u16)r;
}

__global__ void count_kernel(const int* __restrict__ rows, int* __restrict__ deg) {
    int e = blockIdx.x * blockDim.x + threadIdx.x;
    if (e < En) atomicAdd(&deg[rows[e]], 1);
}

__global__ void scan_partial(const int* __restrict__ deg, float* __restrict__ d_is,
                             int* __restrict__ bsum) {
    int tid = threadIdx.x;
    int base = blockIdx.x * CHUNK + tid * 4;
    int s = 0;
#pragma unroll
    for (int i = 0; i < 4; ++i) {
        int idx = base + i;
        if (idx < Nn) {
            int d = deg[idx];
            s += d;
            d_is[idx] = d > 0 ? rsqrtf((float)d) : 0.f;
        }
    }
    __shared__ int sh[256];
    sh[tid] = s;
    __syncthreads();
    for (int o = 128; o > 0; o >>= 1) {
        if (tid < o) sh[tid] += sh[tid + o];
        __syncthreads();
    }
    if (tid == 0) bsum[blockIdx.x] = sh[0];
}

__global__ void scan_top(int* __restrict__ bsum, int* __restrict__ row_ptr) {
    __shared__ int sh[256];
    int tid = threadIdx.x;
    int v = (tid < NB) ? bsum[tid] : 0;
    sh[tid] = v;
    __syncthreads();
    for (int o = 1; o < 256; o <<= 1) {
        int t = (tid >= o) ? sh[tid - o] : 0;
        __syncthreads();
        sh[tid] += t;
        __syncthreads();
    }
    if (tid < NB) bsum[tid] = sh[tid] - v;  // exclusive
    if (tid == 255) row_ptr[Nn] = sh[255];  // == En
}

__global__ void scan_final(const int* __restrict__ deg, const int* __restrict__ bsum,
                           int* __restrict__ row_ptr) {
    int tid = threadIdx.x;
    int base = blockIdx.x * CHUNK + tid * 4;
    int v[4];
    int ts = 0;
#pragma unroll
    for (int i = 0; i < 4; ++i) {
        int idx = base + i;
        v[i] = (idx < Nn) ? deg[idx] : 0;
        ts += v[i];
    }
    __shared__ int sh[256];
    sh[tid] = ts;
    __syncthreads();
    for (int o = 1; o < 256; o <<= 1) {
        int t = (tid >= o) ? sh[tid - o] : 0;
        __syncthreads();
        sh[tid] += t;
        __syncthreads();
    }
    int excl = bsum[blockIdx.x] + sh[tid] - ts;
#pragma unroll
    for (int i = 0; i < 4; ++i) {
        int idx = base + i;
        if (idx < Nn) row_ptr[idx] = excl;
        excl += v[i];
    }
}

// single 4B scatter per edge (val recomputed on-the-fly in spmm)
__global__ void fill_kernel(const int* __restrict__ rows, const int* __restrict__ cols,
                            const int* __restrict__ row_ptr, int* __restrict__ fillc,
                            int* __restrict__ col_s) {
    int e = blockIdx.x * blockDim.x + threadIdx.x;
    if (e >= En) return;
    int r = rows[e], c = cols[e];
    int p = row_ptr[r] + atomicAdd(&fillc[r], 1);
    col_s[p] = c;
}

// emb0 -> out (acc, f32) and cur (bf16)
__global__ void init_kernel(const float* __restrict__ ue, const float* __restrict__ ie,
                            float* __restrict__ out, u16* __restrict__ cur) {
    int i = (blockIdx.x * 256 + threadIdx.x) * 4;
    if (i >= Nn * D) return;
    const float* src = (i < Un * D) ? (ue + i) : (ie + (i - Un * D));
    float4 v = *(const float4*)src;
    *(float4*)(out + i) = v;
    ushort4 q;
    q.x = f2bf(v.x); q.y = f2bf(v.y); q.z = f2bf(v.z); q.w = f2bf(v.w);
    *(ushort4*)(cur + i) = q;
}

// wave per row; 4 edge-groups of 16 lanes; lane holds dims 4l..4l+3.
// B[r] = sum (d_is[r]*d_is[c]) * A[col]; also inv_norm from f32 acc.
__global__ __launch_bounds__(256) void spmm_gnn(const u16* __restrict__ A, u16* __restrict__ B,
                                                const int* __restrict__ row_ptr,
                                                const int* __restrict__ col_s,
                                                const float* __restrict__ d_is,
                                                float* __restrict__ inv_norm) {
    int r = (blockIdx.x * 256 + threadIdx.x) >> 6;
    if (r >= Nn) return;
    int lane = threadIdx.x & 63;
    int g = lane >> 4, l = lane & 15;
    int s = row_ptr[r], t = row_ptr[r + 1];
    float dr = d_is[r];
    float a0 = 0.f, a1 = 0.f, a2 = 0.f, a3 = 0.f;
    for (int j = s + g; j < t; j += 4) {
        int c = col_s[j];
        float v = dr * d_is[c];
        ushort4 q = *(const ushort4*)(A + (size_t)c * D + l * 4);
        a0 += v * bf2f(q.x); a1 += v * bf2f(q.y);
        a2 += v * bf2f(q.z); a3 += v * bf2f(q.w);
    }
    // reduce across the 4 edge-groups
    a0 += __shfl_xor(a0, 16); a1 += __shfl_xor(a1, 16);
    a2 += __shfl_xor(a2, 16); a3 += __shfl_xor(a3, 16);
    a0 += __shfl_xor(a0, 32); a1 += __shfl_xor(a1, 32);
    a2 += __shfl_xor(a2, 32); a3 += __shfl_xor(a3, 32);
    float sq = a0 * a0 + a1 * a1 + a2 * a2 + a3 * a3;
    sq += __shfl_xor(sq, 1); sq += __shfl_xor(sq, 2);
    sq += __shfl_xor(sq, 4); sq += __shfl_xor(sq, 8);
    if (g == 0) {
        ushort4 q;
        q.x = f2bf(a0); q.y = f2bf(a1); q.z = f2bf(a2); q.w = f2bf(a3);
        *(ushort4*)(B + (size_t)r * D + l * 4) = q;
        if (l == 0) inv_norm[r] = 1.f / fmaxf(sqrtf(sq), 1e-12f);
    }
}

// merged score+fine: per edge compute sc from B-gather, accumulate rowsum and
// sc-weighted A-gather in one pass; scores never materialized.
// A (old cur) and B (gnn) are READ-ONLY here; cur_new = B[r] + d_inv*finesum
// goes to the third buffer C (own row only -> no race with the B[c]/A[c]
// gathers of other waves). acc (f32, d_out) += cur_new; fine (f32) to out slot.
__global__ __launch_bounds__(256) void score_fine_kernel(const u16* __restrict__ A,
                                                         const u16* __restrict__ B,
                                                         u16* __restrict__ C,
                                                         const float* __restrict__ inv_norm,
                                                         const int* __restrict__ row_ptr,
                                                         const int* __restrict__ col_s,
                                                         float* __restrict__ out, int layer) {
    int r = (blockIdx.x * 256 + threadIdx.x) >> 6;
    if (r >= Nn) return;
    int lane = threadIdx.x & 63;
    int g = lane >> 4, l = lane & 15;
    int s = row_ptr[r], t = row_ptr[r + 1];
    ushort4 qb = *(const ushort4*)(B + (size_t)r * D + l * 4);
    float b0 = bf2f(qb.x), b1 = bf2f(qb.y), b2 = bf2f(qb.z), b3 = bf2f(qb.w);
    float ir = inv_norm[r];
    float rowsum = 0.f;
    float f0 = 0.f, f1 = 0.f, f2 = 0.f, f3 = 0.f;
    int nit = (t - s + 3) >> 2;
    for (int i = 0; i < nit; ++i) {
        int j = s + i * 4 + g;
        bool valid = j < t;
        int jc = valid ? j : (t - 1);
        int c = col_s[jc];
        ushort4 qc = *(const ushort4*)(B + (size_t)c * D + l * 4);
        ushort4 qa = *(const ushort4*)(A + (size_t)c * D + l * 4);
        float d = b0 * bf2f(qc.x) + b1 * bf2f(qc.y) + b2 * bf2f(qc.z) + b3 * bf2f(qc.w);
        d += __shfl_xor(d, 1); d += __shfl_xor(d, 2);
        d += __shfl_xor(d, 4); d += __shfl_xor(d, 8);
        float sc = (d * ir * inv_norm[c] + 1.f) * 0.5f;
        if (!valid) sc = 0.f;
        rowsum += sc;
        f0 += sc * bf2f(qa.x); f1 += sc * bf2f(qa.y);
        f2 += sc * bf2f(qa.z); f3 += sc * bf2f(qa.w);
    }
    // reduce across the 4 edge-groups (lanes within a group hold identical
    // sc contributions, so xor16/32 sums distinct groups only)
    rowsum += __shfl_xor(rowsum, 16);
    rowsum += __shfl_xor(rowsum, 32);
    f0 += __shfl_xor(f0, 16); f1 += __shfl_xor(f1, 16);
    f2 += __shfl_xor(f2, 16); f3 += __shfl_xor(f3, 16);
    f0 += __shfl_xor(f0, 32); f1 += __shfl_xor(f1, 32);
    f2 += __shfl_xor(f2, 32); f3 += __shfl_xor(f3, 32);
    float di = rowsum > 0.f ? 1.f / rowsum : 0.f;
    f0 *= di; f1 *= di; f2 *= di; f3 *= di;
    if (g == 0) {
        size_t ro = (size_t)r * D + l * 4;
        float c0 = bf2f(qb.x) + f0, c1 = bf2f(qb.y) + f1;
        float c2 = bf2f(qb.z) + f2, c3 = bf2f(qb.w) + f3;
        ushort4 qn;
        qn.x = f2bf(c0); qn.y = f2bf(c1); qn.z = f2bf(c2); qn.w = f2bf(c3);
        *(ushort4*)(C + ro) = qn;
        float4* av = (float4*)(out + ro);
        float4 a = *av;
        a.x += c0; a.y += c1; a.z += c2; a.w += c3;
        *av = a;
        size_t fo;
        if (r < Un)
            fo = (size_t)Nn * D + (size_t)layer * Un * D + (size_t)r * D + l * 4;
        else
            fo = (size_t)Nn * D + (size_t)Ln * Un * D + (size_t)layer * In * D
                 + (size_t)(r - Un) * D + l * 4;
        float4 fv; fv.x = f0; fv.y = f1; fv.z = f2; fv.w = f3;
        *(float4*)(out + fo) = fv;
    }
}

}  // namespace

extern "C" void kernel_launch(void* const* d_in, const int* in_sizes, int n_in,
                              void* d_out, int out_size, void* d_ws, size_t ws_size,
                              hipStream_t stream) {
    const float* user_emb = (const float*)d_in[0];
    const float* item_emb = (const float*)d_in[1];
    const int* rows = (const int*)d_in[2];
    const int* cols = (const int*)d_in[3];
    float* out = (float*)d_out;

    char* ws = (char*)d_ws;
    size_t off = 0;
    auto alloc = [&](size_t bytes) -> void* {
        void* p = ws + off;
        off += (bytes + 255) & ~size_t(255);
        return p;
    };
    u16*   buf0    = (u16*)  alloc((size_t)Nn * D * 2);   // 19.2 MB
    u16*   buf1    = (u16*)  alloc((size_t)Nn * D * 2);   // 19.2 MB
    u16*   buf2    = (u16*)  alloc((size_t)Nn * D * 2);   // 19.2 MB
    int*   col_s   = (int*)  alloc((size_t)En * 4);       // 8 MB
    int*   deg     = (int*)  alloc((size_t)Nn * 4);
    int*   row_ptr = (int*)  alloc((size_t)(Nn + 1) * 4);
    int*   fillc   = (int*)  alloc((size_t)Nn * 4);
    float* d_is    = (float*)alloc((size_t)Nn * 4);
    float* inv_norm= (float*)alloc((size_t)Nn * 4);
    int*   bsum    = (int*)  alloc(4096);
    (void)ws_size; (void)in_sizes; (void)n_in; (void)out_size;

    hipMemsetAsync(deg, 0, (size_t)Nn * 4, stream);
    hipMemsetAsync(fillc, 0, (size_t)Nn * 4, stream);

    init_kernel<<<(Nn * D / 4 + 255) / 256, 256, 0, stream>>>(user_emb, item_emb, out, buf0);

    const int EB = (En + 255) / 256;
    count_kernel<<<EB, 256, 0, stream>>>(rows, deg);
    scan_partial<<<NB, 256, 0, stream>>>(deg, d_is, bsum);
    scan_top<<<1, 256, 0, stream>>>(bsum, row_ptr);
    scan_final<<<NB, 256, 0, stream>>>(deg, bsum, row_ptr);
    fill_kernel<<<EB, 256, 0, stream>>>(rows, cols, row_ptr, fillc, col_s);

    const int RB = Nn / 4;  // 37500 blocks, 4 waves/block, 1 wave/row
    u16* P = buf0;  // cur
    u16* Q = buf1;  // gnn
    u16* R = buf2;  // cur_new
    for (int l = 0; l < Ln; ++l) {
        spmm_gnn<<<RB, 256, 0, stream>>>(P, Q, row_ptr, col_s, d_is, inv_norm);
        score_fine_kernel<<<RB, 256, 0, stream>>>(P, Q, R, inv_norm, row_ptr, col_s, out, l);
        u16* t0 = P, *t1 = Q, *t2 = R;
        P = t2; Q = t0; R = t1;  // cur_new becomes cur; old buffers recycled
    }
}